// Round 1
// baseline (848.603 us; speedup 1.0000x reference)
//
#include <hip/hip_runtime.h>
#include <hip/hip_bf16.h>

// Problem constants
constexpr int NH  = 12;    // heads
constexpr int SEQ = 2048;  // sequence
constexpr int DHD = 64;    // head dim
constexpr int DIM = 768;   // model dim
// B = 2, GAMMA = 0.5, SCALE*SMOOTHING = 0.125 (folded into Q projections)

typedef __bf16 bf16x8 __attribute__((ext_vector_type(8)));
typedef __bf16 bf16x4 __attribute__((ext_vector_type(4)));
typedef float  f32x4  __attribute__((ext_vector_type(4)));

#define MFMA16(a, b, c) __builtin_amdgcn_mfma_f32_16x16x32_bf16((a), (b), (c), 0, 0, 0)

// ---------------------------------------------------------------------------
// Kernel 1: projections. z selects which GEMM. A (f32) [M x 768] @ W (f32)
// [768 x 768] -> bf16 output in permuted layout. n -> (d = n/12, h = n%12).
//   mode 0: out[((b*NH+h)*SEQ+s)*DHD+d]   (Qi / Ki)
//   mode 1: out[((b*NH+h)*DHD+d)*SEQ+s]   (V transposed)
//   mode 2: out[(h*SEQ+s)*DHD+d]          (Qp / Kp)
// Tile: BM=64, BN=192, BK=32; 4 waves in 2x2; wave tile 32x96.
// ---------------------------------------------------------------------------
__global__ __launch_bounds__(256) void proj_kernel(
    const float* __restrict__ inp, const float* __restrict__ pos,
    const float* __restrict__ Wqi, const float* __restrict__ Wki,
    const float* __restrict__ Wqp, const float* __restrict__ Wkp,
    const float* __restrict__ Wvv,
    __bf16* __restrict__ Qi, __bf16* __restrict__ Ki, __bf16* __restrict__ Vt,
    __bf16* __restrict__ Qp, __bf16* __restrict__ Kp)
{
    const int z = blockIdx.z;
    const float* A; const float* W; __bf16* outp; int M; int mode; float scale = 1.0f;
    if (z == 0)      { A = inp; W = Wqi; outp = Qi; M = 4096; mode = 0; scale = 0.125f; }
    else if (z == 1) { A = inp; W = Wki; outp = Ki; M = 4096; mode = 0; }
    else if (z == 2) { A = inp; W = Wvv; outp = Vt; M = 4096; mode = 1; }
    else if (z == 3) { A = pos; W = Wqp; outp = Qp; M = 2048; mode = 2; scale = 0.125f; }
    else             { A = pos; W = Wkp; outp = Kp; M = 2048; mode = 2; }

    const int m0 = blockIdx.y * 64;
    if (m0 >= M) return;
    const int n0 = blockIdx.x * 192;

    __shared__ __bf16 Al[64][32];
    __shared__ __bf16 Wl[192][32];   // transposed: Wl[n_local][k_local]

    const int tid = threadIdx.x;
    const int lane = tid & 63, wv = tid >> 6;
    const int wm = wv >> 1, wn = wv & 1;
    const int l15 = lane & 15, lg = lane >> 4;

    f32x4 c[2][6] = {};

    for (int kt = 0; kt < 24; ++kt) {
        const int k0 = kt * 32;
        __syncthreads();
        {   // stage A tile 64x32 (f32 -> bf16)
            const int r = tid >> 3, kq = tid & 7;
            #pragma unroll
            for (int rep = 0; rep < 2; ++rep) {
                const float4 v = *reinterpret_cast<const float4*>(
                    &A[(size_t)(m0 + r + rep * 32) * DIM + k0 + kq * 4]);
                bf16x4 t;
                t[0] = (__bf16)v.x; t[1] = (__bf16)v.y; t[2] = (__bf16)v.z; t[3] = (__bf16)v.w;
                *reinterpret_cast<bf16x4*>(&Al[r + rep * 32][kq * 4]) = t;
            }
        }
        // stage W tile 32x192, transposed into Wl[n][k]
        for (int idx = tid; idx < 32 * 48; idx += 256) {
            const int k = idx / 48, nq = idx - k * 48;
            const float4 v = *reinterpret_cast<const float4*>(
                &W[(size_t)(k0 + k) * DIM + n0 + nq * 4]);
            Wl[nq * 4 + 0][k] = (__bf16)v.x;
            Wl[nq * 4 + 1][k] = (__bf16)v.y;
            Wl[nq * 4 + 2][k] = (__bf16)v.z;
            Wl[nq * 4 + 3][k] = (__bf16)v.w;
        }
        __syncthreads();

        bf16x8 a[2], b[6];
        #pragma unroll
        for (int mf = 0; mf < 2; ++mf)
            a[mf] = *reinterpret_cast<const bf16x8*>(&Al[wm * 32 + mf * 16 + l15][lg * 8]);
        #pragma unroll
        for (int nf = 0; nf < 6; ++nf)
            b[nf] = *reinterpret_cast<const bf16x8*>(&Wl[wn * 96 + nf * 16 + l15][lg * 8]);
        #pragma unroll
        for (int mf = 0; mf < 2; ++mf)
            #pragma unroll
            for (int nf = 0; nf < 6; ++nf)
                c[mf][nf] = MFMA16(a[mf], b[nf], c[mf][nf]);
    }

    // epilogue: permuted scatter store (accepted inefficiency for round 1)
    #pragma unroll
    for (int mf = 0; mf < 2; ++mf)
        #pragma unroll
        for (int nf = 0; nf < 6; ++nf)
            #pragma unroll
            for (int r = 0; r < 4; ++r) {
                const int m = m0 + wm * 32 + mf * 16 + lg * 4 + r;
                const int n = n0 + wn * 96 + nf * 16 + l15;
                const float val = c[mf][nf][r] * scale;
                const int d = n / 12, hh = n - d * 12;
                size_t idx;
                if (mode == 0) {
                    const int b_ = m >> 11, s_ = m & 2047;
                    idx = (((size_t)b_ * NH + hh) * SEQ + s_) * DHD + d;
                } else if (mode == 1) {
                    const int b_ = m >> 11, s_ = m & 2047;
                    idx = (((size_t)b_ * NH + hh) * DHD + d) * SEQ + s_;
                } else {
                    idx = ((size_t)hh * SEQ + m) * DHD + d;
                }
                outp[idx] = (__bf16)val;
            }
}

// ---------------------------------------------------------------------------
// Kernel 2: softmax stats (m, l) per row. bb in {0,1}: content stream per
// batch; bb == 2: positional stream. Block: 4 waves, each wave owns 32 rows,
// loops all j. K tile staged in LDS, shared by the 4 waves.
// ---------------------------------------------------------------------------
__global__ __launch_bounds__(256) void stats_kernel(
    const __bf16* __restrict__ Qi, const __bf16* __restrict__ Ki,
    const __bf16* __restrict__ Qp, const __bf16* __restrict__ Kp,
    float* __restrict__ m_ws, float* __restrict__ l_ws)
{
    const int it = blockIdx.x, h = blockIdx.y, bb = blockIdx.z;
    const int tid = threadIdx.x, lane = tid & 63, wv = tid >> 6;
    const int l15 = lane & 15, lg = lane >> 4;
    const int i0 = it * 128 + wv * 32;

    const __bf16* Q = (bb < 2) ? Qi + ((size_t)bb * NH + h) * SEQ * DHD
                               : Qp + (size_t)h * SEQ * DHD;
    const __bf16* K = (bb < 2) ? Ki + ((size_t)bb * NH + h) * SEQ * DHD
                               : Kp + (size_t)h * SEQ * DHD;

    __shared__ __bf16 Klds[32][64];

    bf16x8 a[2][2];
    #pragma unroll
    for (int mf = 0; mf < 2; ++mf)
        #pragma unroll
        for (int ks = 0; ks < 2; ++ks)
            a[mf][ks] = *reinterpret_cast<const bf16x8*>(
                &Q[(size_t)(i0 + mf * 16 + l15) * DHD + ks * 32 + lg * 8]);

    float mr[2][4], lr[2][4];
    #pragma unroll
    for (int mf = 0; mf < 2; ++mf)
        #pragma unroll
        for (int r = 0; r < 4; ++r) { mr[mf][r] = -1e30f; lr[mf][r] = 0.0f; }

    for (int jt = 0; jt < 64; ++jt) {
        const int j0 = jt * 32;
        __syncthreads();
        {   // stage K tile 32x64
            const int row = tid >> 3, kq = tid & 7;
            *reinterpret_cast<bf16x8*>(&Klds[row][kq * 8]) =
                *reinterpret_cast<const bf16x8*>(&K[(size_t)(j0 + row) * DHD + kq * 8]);
        }
        __syncthreads();

        f32x4 c[2][2] = {};
        #pragma unroll
        for (int ks = 0; ks < 2; ++ks) {
            const bf16x8 b0 = *reinterpret_cast<const bf16x8*>(&Klds[l15][ks * 32 + lg * 8]);
            const bf16x8 b1 = *reinterpret_cast<const bf16x8*>(&Klds[16 + l15][ks * 32 + lg * 8]);
            #pragma unroll
            for (int mf = 0; mf < 2; ++mf) {
                c[mf][0] = MFMA16(a[mf][ks], b0, c[mf][0]);
                c[mf][1] = MFMA16(a[mf][ks], b1, c[mf][1]);
            }
        }
        // per-lane online (m, l) over this lane's two columns
        #pragma unroll
        for (int mf = 0; mf < 2; ++mf)
            #pragma unroll
            for (int r = 0; r < 4; ++r) {
                const float x0 = c[mf][0][r], x1 = c[mf][1][r];
                const float mn = fmaxf(mr[mf][r], fmaxf(x0, x1));
                lr[mf][r] = lr[mf][r] * __expf(mr[mf][r] - mn)
                          + __expf(x0 - mn) + __expf(x1 - mn);
                mr[mf][r] = mn;
            }
    }

    // merge across the 16 lanes that share rows (xor 1,2,4,8)
    #pragma unroll
    for (int msk = 1; msk < 16; msk <<= 1)
        #pragma unroll
        for (int mf = 0; mf < 2; ++mf)
            #pragma unroll
            for (int r = 0; r < 4; ++r) {
                const float mo = __shfl_xor(mr[mf][r], msk);
                const float lo = __shfl_xor(lr[mf][r], msk);
                const float mn = fmaxf(mr[mf][r], mo);
                lr[mf][r] = lr[mf][r] * __expf(mr[mf][r] - mn) + lo * __expf(mo - mn);
                mr[mf][r] = mn;
            }

    if (l15 == 0) {
        const size_t base = ((size_t)bb * NH + h) * SEQ + i0;
        #pragma unroll
        for (int mf = 0; mf < 2; ++mf)
            #pragma unroll
            for (int r = 0; r < 4; ++r) {
                const int i = mf * 16 + lg * 4 + r;
                m_ws[base + i] = mr[mf][r];
                l_ws[base + i] = lr[mf][r];
            }
    }
}

// ---------------------------------------------------------------------------
// Kernel 3: emit blended probabilities (coalesced [b,i,j,h] writes via LDS
// transpose) + fused PV accumulation (atomicAdd into attn_pre).
// Block: (b, 16-row i-tile, j-quarter). 4 waves; wave w owns heads 3w..3w+2.
// ---------------------------------------------------------------------------
__global__ __launch_bounds__(256) void emit_kernel(
    const __bf16* __restrict__ Qi, const __bf16* __restrict__ Ki,
    const __bf16* __restrict__ Qp, const __bf16* __restrict__ Kp,
    const __bf16* __restrict__ Vt,
    const float* __restrict__ m_ws, const float* __restrict__ l_ws,
    float* __restrict__ out1, float* __restrict__ attn_pre)
{
    const int it = blockIdx.x, js = blockIdx.y, b = blockIdx.z;
    const int i0 = it * 16;
    const int tid = threadIdx.x, lane = tid & 63, wv = tid >> 6;
    const int l15 = lane & 15, lg = lane >> 4;

    __shared__ __bf16 pbuf[12][16][32];
    __shared__ float  ml[12][16][4];   // m_inp, 1/l_inp, m_pos, 1/l_pos

    if (tid < 192) {
        const int h = tid >> 4, i = tid & 15;
        const size_t bi  = ((size_t)b * NH + h) * SEQ + i0 + i;
        const size_t ppi = ((size_t)2 * NH + h) * SEQ + i0 + i;
        ml[h][i][0] = m_ws[bi];
        ml[h][i][1] = 1.0f / l_ws[bi];
        ml[h][i][2] = m_ws[ppi];
        ml[h][i][3] = 1.0f / l_ws[ppi];
    }
    __syncthreads();

    // persistent Q fragments: [head][stream][kstep]
    bf16x8 aQ[3][2][2];
    #pragma unroll
    for (int hh = 0; hh < 3; ++hh) {
        const int h = wv * 3 + hh;
        #pragma unroll
        for (int ks = 0; ks < 2; ++ks) {
            aQ[hh][0][ks] = *reinterpret_cast<const bf16x8*>(
                &Qi[(((size_t)b * NH + h) * SEQ + i0 + l15) * DHD + ks * 32 + lg * 8]);
            aQ[hh][1][ks] = *reinterpret_cast<const bf16x8*>(
                &Qp[((size_t)h * SEQ + i0 + l15) * DHD + ks * 32 + lg * 8]);
        }
    }

    f32x4 acc[3][4] = {};   // PV accumulators: [head][d-frag]

    for (int jt = 0; jt < 16; ++jt) {
        const int j0 = js * 512 + jt * 32;

        #pragma unroll
        for (int hh = 0; hh < 3; ++hh) {
            const int h = wv * 3 + hh;
            const __bf16* Kib = Ki + ((size_t)b * NH + h) * SEQ * DHD;
            const __bf16* Kpb = Kp + (size_t)h * SEQ * DHD;

            f32x4 ci[2] = {}, cq[2] = {};
            #pragma unroll
            for (int ks = 0; ks < 2; ++ks)
                #pragma unroll
                for (int nf = 0; nf < 2; ++nf) {
                    const bf16x8 bi_ = *reinterpret_cast<const bf16x8*>(
                        &Kib[(size_t)(j0 + nf * 16 + l15) * DHD + ks * 32 + lg * 8]);
                    const bf16x8 bp_ = *reinterpret_cast<const bf16x8*>(
                        &Kpb[(size_t)(j0 + nf * 16 + l15) * DHD + ks * 32 + lg * 8]);
                    ci[nf] = MFMA16(aQ[hh][0][ks], bi_, ci[nf]);
                    cq[nf] = MFMA16(aQ[hh][1][ks], bp_, cq[nf]);
                }

            // softmax + gamma blend -> pbuf
            #pragma unroll
            for (int nf = 0; nf < 2; ++nf)
                #pragma unroll
                for (int r = 0; r < 4; ++r) {
                    const int i = lg * 4 + r;
                    const float pi_ = __expf(ci[nf][r] - ml[h][i][0]) * ml[h][i][1];
                    const float pq_ = __expf(cq[nf][r] - ml[h][i][2]) * ml[h][i][3];
                    pbuf[h][i][nf * 16 + l15] = (__bf16)(0.5f * pi_ + 0.5f * pq_);
                }

            // PV: A = P (16x32) from pbuf (same-wave RAW, compiler waits),
            //     B = V (32j x 64d) from transposed-V global layout
            const bf16x8 ap = *reinterpret_cast<const bf16x8*>(&pbuf[h][l15][lg * 8]);
            #pragma unroll
            for (int nf = 0; nf < 4; ++nf) {
                const bf16x8 bv = *reinterpret_cast<const bf16x8*>(
                    &Vt[(((size_t)b * NH + h) * DHD + nf * 16 + l15) * SEQ + j0 + lg * 8]);
                acc[hh][nf] = MFMA16(ap, bv, acc[hh][nf]);
            }
        }
        __syncthreads();

        // coalesced write of [i][j][h] chunks: 12 consecutive floats per (i,j)
        #pragma unroll
        for (int rep = 0; rep < 2; ++rep) {
            const int pair = rep * 256 + tid;
            const int i = pair >> 5, jj = pair & 31;
            const size_t base = (((size_t)(b * SEQ + i0 + i)) * SEQ + j0 + jj) * 12;
            f32x4 v0, v1, v2;
            #pragma unroll
            for (int q = 0; q < 4; ++q) {
                v0[q] = (float)pbuf[q][i][jj];
                v1[q] = (float)pbuf[4 + q][i][jj];
                v2[q] = (float)pbuf[8 + q][i][jj];
            }
            *reinterpret_cast<f32x4*>(&out1[base])     = v0;
            *reinterpret_cast<f32x4*>(&out1[base + 4]) = v1;
            *reinterpret_cast<f32x4*>(&out1[base + 8]) = v2;
        }
        __syncthreads();
    }

    // PV epilogue: j-quarter partial sums -> atomicAdd
    #pragma unroll
    for (int hh = 0; hh < 3; ++hh) {
        const int h = wv * 3 + hh;
        #pragma unroll
        for (int nf = 0; nf < 4; ++nf)
            #pragma unroll
            for (int r = 0; r < 4; ++r) {
                const int i = lg * 4 + r;
                atomicAdd(&attn_pre[((size_t)(b * SEQ + i0 + i)) * DIM + h * DHD + nf * 16 + l15],
                          acc[hh][nf][r]);
            }
    }
}

// ---------------------------------------------------------------------------
// Kernel 4: final GEMM attn_pre (f32) @ Wo (f32) -> out0 (f32, natural layout)
// ---------------------------------------------------------------------------
__global__ __launch_bounds__(256) void final_kernel(
    const float* __restrict__ A, const float* __restrict__ W, float* __restrict__ out0)
{
    const int m0 = blockIdx.y * 64;
    const int n0 = blockIdx.x * 192;

    __shared__ __bf16 Al[64][32];
    __shared__ __bf16 Wl[192][32];

    const int tid = threadIdx.x;
    const int lane = tid & 63, wv = tid >> 6;
    const int wm = wv >> 1, wn = wv & 1;
    const int l15 = lane & 15, lg = lane >> 4;

    f32x4 c[2][6] = {};

    for (int kt = 0; kt < 24; ++kt) {
        const int k0 = kt * 32;
        __syncthreads();
        {
            const int r = tid >> 3, kq = tid & 7;
            #pragma unroll
            for (int rep = 0; rep < 2; ++rep) {
                const float4 v = *reinterpret_cast<const float4*>(
                    &A[(size_t)(m0 + r + rep * 32) * DIM + k0 + kq * 4]);
                bf16x4 t;
                t[0] = (__bf16)v.x; t[1] = (__bf16)v.y; t[2] = (__bf16)v.z; t[3] = (__bf16)v.w;
                *reinterpret_cast<bf16x4*>(&Al[r + rep * 32][kq * 4]) = t;
            }
        }
        for (int idx = tid; idx < 32 * 48; idx += 256) {
            const int k = idx / 48, nq = idx - k * 48;
            const float4 v = *reinterpret_cast<const float4*>(
                &W[(size_t)(k0 + k) * DIM + n0 + nq * 4]);
            Wl[nq * 4 + 0][k] = (__bf16)v.x;
            Wl[nq * 4 + 1][k] = (__bf16)v.y;
            Wl[nq * 4 + 2][k] = (__bf16)v.z;
            Wl[nq * 4 + 3][k] = (__bf16)v.w;
        }
        __syncthreads();

        bf16x8 a[2], b[6];
        #pragma unroll
        for (int mf = 0; mf < 2; ++mf)
            a[mf] = *reinterpret_cast<const bf16x8*>(&Al[wm * 32 + mf * 16 + l15][lg * 8]);
        #pragma unroll
        for (int nf = 0; nf < 6; ++nf)
            b[nf] = *reinterpret_cast<const bf16x8*>(&Wl[wn * 96 + nf * 16 + l15][lg * 8]);
        #pragma unroll
        for (int mf = 0; mf < 2; ++mf)
            #pragma unroll
            for (int nf = 0; nf < 6; ++nf)
                c[mf][nf] = MFMA16(a[mf], b[nf], c[mf][nf]);
    }

    #pragma unroll
    for (int mf = 0; mf < 2; ++mf)
        #pragma unroll
        for (int nf = 0; nf < 6; ++nf)
            #pragma unroll
            for (int r = 0; r < 4; ++r) {
                const int m = m0 + wm * 32 + mf * 16 + lg * 4 + r;
                const int n = n0 + wn * 96 + nf * 16 + l15;
                out0[(size_t)m * DIM + n] = c[mf][nf][r];
            }
}

// ---------------------------------------------------------------------------
extern "C" void kernel_launch(void* const* d_in, const int* in_sizes, int n_in,
                              void* d_out, int out_size, void* d_ws, size_t ws_size,
                              hipStream_t stream)
{
    (void)in_sizes; (void)n_in; (void)out_size; (void)ws_size;

    const float* inp = (const float*)d_in[0];
    const float* pos = (const float*)d_in[1];
    const float* Wqi = (const float*)d_in[2];
    const float* Wki = (const float*)d_in[3];
    const float* Wqp = (const float*)d_in[4];
    const float* Wkp = (const float*)d_in[5];
    const float* Wvv = (const float*)d_in[6];
    const float* Wo  = (const float*)d_in[7];

    char* w = (char*)d_ws;
    __bf16* Qi = (__bf16*)w; w += (size_t)2 * NH * SEQ * DHD * 2;   // 6 MB
    __bf16* Ki = (__bf16*)w; w += (size_t)2 * NH * SEQ * DHD * 2;   // 6 MB
    __bf16* Vt = (__bf16*)w; w += (size_t)2 * NH * SEQ * DHD * 2;   // 6 MB (transposed [b][h][d][s])
    __bf16* Qp = (__bf16*)w; w += (size_t)NH * SEQ * DHD * 2;       // 3 MB
    __bf16* Kp = (__bf16*)w; w += (size_t)NH * SEQ * DHD * 2;       // 3 MB
    float* m_ws = (float*)w; w += (size_t)3 * NH * SEQ * 4;         // 288 KB
    float* l_ws = (float*)w; w += (size_t)3 * NH * SEQ * 4;         // 288 KB
    float* attn_pre = (float*)w; w += (size_t)4096 * DIM * 4;       // 12 MB

    float* out0 = (float*)d_out;                  // [2,2048,768]
    float* out1 = out0 + (size_t)2 * SEQ * DIM;   // [2,2048,2048,12]

    hipMemsetAsync(attn_pre, 0, (size_t)4096 * DIM * 4, stream);

    hipLaunchKernelGGL(proj_kernel, dim3(4, 64, 5), dim3(256), 0, stream,
                       inp, pos, Wqi, Wki, Wqp, Wkp, Wvv, Qi, Ki, Vt, Qp, Kp);
    hipLaunchKernelGGL(stats_kernel, dim3(16, 12, 3), dim3(256), 0, stream,
                       Qi, Ki, Qp, Kp, m_ws, l_ws);
    hipLaunchKernelGGL(emit_kernel, dim3(128, 4, 2), dim3(256), 0, stream,
                       Qi, Ki, Qp, Kp, Vt, m_ws, l_ws, out1, attn_pre);
    hipLaunchKernelGGL(final_kernel, dim3(4, 64, 1), dim3(256), 0, stream,
                       attn_pre, Wo, out0);
}